// Round 1
// baseline (245.072 us; speedup 1.0000x reference)
//
#include <hip/hip_runtime.h>
#include <math.h>

// TopK router: logits = x @ W^T + b ; top-2 over E=64 ; sparse softmax.
// x: [T=16384, D=2048] f32, W: [E=64, D=2048] f32, b: [64] f32 (zeros).
// d_out: [T*64] router probs f32, then [T*2] top-k indices written as f32.
//
// Layout: lane = expert (64 lanes = 64 experts), each wave owns 16 tokens.
// W row is per-lane (L2-resident, 512 KB total, reused across 16 tokens);
// x reads are wave-uniform -> scalar loads (SGPR broadcast).
// Accumulate fp32 fma-chains of 8 into a double accumulator so the logit
// error (~1e-6) is far below typical rank-2/3 gaps (~0.1) -> indices match
// the numpy reference; top-2 compare done in double, ties -> lower index
// (jax.lax.top_k semantics).

#define ROUTER_D 2048
#define ROUTER_E 64
#define TOKENS_PER_WAVE 16
#define WAVES_PER_BLOCK 4
#define KB_STEP 8

__global__ __launch_bounds__(256, 1) void topk_router_kernel(
    const float* __restrict__ x,
    const float* __restrict__ W,
    const float* __restrict__ b,
    float* __restrict__ out_router,
    float* __restrict__ out_idx,
    int total_tokens)
{
    const int lane = threadIdx.x & 63;
    const int wave = __builtin_amdgcn_readfirstlane((int)(threadIdx.x >> 6));
    const int tok0 = (blockIdx.x * WAVES_PER_BLOCK + wave) * TOKENS_PER_WAVE;
    if (tok0 >= total_tokens) return;

    double acc[TOKENS_PER_WAVE];
#pragma unroll
    for (int t = 0; t < TOKENS_PER_WAVE; ++t) acc[t] = 0.0;

    const float* wrow = W + (size_t)lane * ROUTER_D;
    const float* xbase = x + (size_t)tok0 * ROUTER_D;

    for (int kb = 0; kb < ROUTER_D; kb += KB_STEP) {
        const float4 w0 = *(const float4*)(wrow + kb);
        const float4 w1 = *(const float4*)(wrow + kb + 4);
#pragma unroll
        for (int t = 0; t < TOKENS_PER_WAVE; ++t) {
            const float* xr = xbase + (size_t)t * ROUTER_D + kb;
            const float4 x0 = *(const float4*)(xr);
            const float4 x1 = *(const float4*)(xr + 4);
            float s = x0.x * w0.x;
            s = fmaf(x0.y, w0.y, s);
            s = fmaf(x0.z, w0.z, s);
            s = fmaf(x0.w, w0.w, s);
            s = fmaf(x1.x, w1.x, s);
            s = fmaf(x1.y, w1.y, s);
            s = fmaf(x1.z, w1.z, s);
            s = fmaf(x1.w, w1.w, s);
            acc[t] += (double)s;
        }
    }

    const double bias = (double)b[lane];

    for (int t = 0; t < TOKENS_PER_WAVE; ++t) {
        const int token = tok0 + t;
        if (token >= total_tokens) break;
        const double v = acc[t] + bias;

        // --- argmax #1 (value desc, tie -> lower lane), butterfly over 64 lanes
        double bestv = v;
        int besti = lane;
#pragma unroll
        for (int off = 32; off > 0; off >>= 1) {
            double ov = __shfl_xor(bestv, off, 64);
            int oi = __shfl_xor(besti, off, 64);
            if (ov > bestv || (ov == bestv && oi < besti)) { bestv = ov; besti = oi; }
        }

        // --- argmax #2 excluding winner
        double v2 = (lane == besti) ? -INFINITY : v;
        double best2v = v2;
        int best2i = lane;
#pragma unroll
        for (int off = 32; off > 0; off >>= 1) {
            double ov = __shfl_xor(best2v, off, 64);
            int oi = __shfl_xor(best2i, off, 64);
            if (ov > best2v || (ov == best2v && oi < best2i)) { best2v = ov; best2i = oi; }
        }

        // --- 2-element softmax: p1 = 1/(1+e2), p2 = e2/(1+e2), rest exactly 0
        const float e2 = expf((float)(best2v - bestv));
        const float denom = 1.0f + e2;
        const float p1 = 1.0f / denom;
        const float p2 = e2 / denom;

        float outv = 0.0f;
        if (lane == besti) outv = p1;
        else if (lane == best2i) outv = p2;
        out_router[(size_t)token * ROUTER_E + lane] = outv;

        if (lane == 0) {
            out_idx[(size_t)token * 2 + 0] = (float)besti;
            out_idx[(size_t)token * 2 + 1] = (float)best2i;
        }
    }
}

extern "C" void kernel_launch(void* const* d_in, const int* in_sizes, int n_in,
                              void* d_out, int out_size, void* d_ws, size_t ws_size,
                              hipStream_t stream) {
    const float* x = (const float*)d_in[0];
    const float* W = (const float*)d_in[1];
    const float* b = (const float*)d_in[2];

    const int E = in_sizes[2];                 // 64
    const int D = in_sizes[1] / E;             // 2048
    const int T = in_sizes[0] / D;             // 16384
    (void)E; (void)D;

    float* out_router = (float*)d_out;
    float* out_idx = out_router + (size_t)T * ROUTER_E;

    const int tokens_per_block = WAVES_PER_BLOCK * TOKENS_PER_WAVE; // 64
    const int grid = (T + tokens_per_block - 1) / tokens_per_block; // 256

    topk_router_kernel<<<grid, 256, 0, stream>>>(x, W, b, out_router, out_idx, T);
}

// Round 2
// 122.301 us; speedup vs baseline: 2.0039x; 2.0039x over previous
//
#include <hip/hip_runtime.h>
#include <math.h>

// TopK router: logits = x @ W^T + b ; top-2 over E=64 ; sparse softmax.
// x: [T=16384, D=2048] f32, W: [E=64, D=2048] f32, b: [64] f32.
// d_out: [T*64] router probs f32, then [T*2] top-k indices written as f32.
//
// R1 redesign: block = 16 tokens, 4 waves; each wave computes a D-quarter
// (512 elems) of the dot for all 16 tokens (lane = expert). Partials (f64)
// combined via LDS; epilogue (top-2 + softmax) parallelized wave-per-4-tokens.
// Grid = 1024 blocks -> 4 blocks/CU -> 16 waves/CU (~50% occupancy), vs R0's
// 1 wave/SIMD which left VALUBusy at 21%. W L2 traffic unchanged (512 MB).

#define ROUTER_D 2048
#define ROUTER_E 64
#define TPB 16      // tokens per block
#define DSPLIT 4    // waves per block, each owns D/DSPLIT
#define DQ (ROUTER_D / DSPLIT)  // 512

__global__ __launch_bounds__(256, 4) void topk_router_kernel(
    const float* __restrict__ x,
    const float* __restrict__ W,
    const float* __restrict__ b,
    float* __restrict__ out_router,
    float* __restrict__ out_idx,
    int total_tokens)
{
    const int lane = threadIdx.x & 63;
    const int wq = __builtin_amdgcn_readfirstlane((int)(threadIdx.x >> 6)); // D-quarter id
    const int tok0 = blockIdx.x * TPB;

    __shared__ double partial[DSPLIT][TPB][ROUTER_E];  // 32 KB

    double acc[TPB];
#pragma unroll
    for (int t = 0; t < TPB; ++t) acc[t] = 0.0;

    const float* wrow  = W + (size_t)lane * ROUTER_D + wq * DQ;
    const float* xbase = x + (size_t)tok0 * ROUTER_D + wq * DQ;

    for (int kb = 0; kb < DQ; kb += 8) {
        const float4 w0 = *(const float4*)(wrow + kb);
        const float4 w1 = *(const float4*)(wrow + kb + 4);
#pragma unroll
        for (int t = 0; t < TPB; ++t) {
            const float* xr = xbase + (size_t)t * ROUTER_D + kb;
            const float4 x0 = *(const float4*)(xr);
            const float4 x1 = *(const float4*)(xr + 4);
            float s = x0.x * w0.x;
            s = fmaf(x0.y, w0.y, s);
            s = fmaf(x0.z, w0.z, s);
            s = fmaf(x0.w, w0.w, s);
            s = fmaf(x1.x, w1.x, s);
            s = fmaf(x1.y, w1.y, s);
            s = fmaf(x1.z, w1.z, s);
            s = fmaf(x1.w, w1.w, s);
            acc[t] += (double)s;
        }
    }

#pragma unroll
    for (int t = 0; t < TPB; ++t) partial[wq][t][lane] = acc[t];
    __syncthreads();

    const double bias = (double)b[lane];

    // Epilogue: wave wq owns tokens [wq*4, wq*4+4)
#pragma unroll
    for (int tt = 0; tt < TPB / DSPLIT; ++tt) {
        const int t = wq * (TPB / DSPLIT) + tt;
        const int token = tok0 + t;
        if (token >= total_tokens) break;

        const double v = partial[0][t][lane] + partial[1][t][lane]
                       + partial[2][t][lane] + partial[3][t][lane] + bias;

        // --- argmax #1 (value desc, tie -> lower lane), butterfly over 64 lanes
        double bestv = v;
        int besti = lane;
#pragma unroll
        for (int off = 32; off > 0; off >>= 1) {
            double ov = __shfl_xor(bestv, off, 64);
            int oi = __shfl_xor(besti, off, 64);
            if (ov > bestv || (ov == bestv && oi < besti)) { bestv = ov; besti = oi; }
        }

        // --- argmax #2 excluding winner
        double v2 = (lane == besti) ? -INFINITY : v;
        double best2v = v2;
        int best2i = lane;
#pragma unroll
        for (int off = 32; off > 0; off >>= 1) {
            double ov = __shfl_xor(best2v, off, 64);
            int oi = __shfl_xor(best2i, off, 64);
            if (ov > best2v || (ov == best2v && oi < best2i)) { best2v = ov; best2i = oi; }
        }

        // --- 2-element softmax: p1 = 1/(1+e2), p2 = e2/(1+e2), rest exactly 0
        const float e2 = expf((float)(best2v - bestv));
        const float denom = 1.0f + e2;
        const float p1 = 1.0f / denom;
        const float p2 = e2 / denom;

        float outv = 0.0f;
        if (lane == besti) outv = p1;
        else if (lane == best2i) outv = p2;
        out_router[(size_t)token * ROUTER_E + lane] = outv;

        if (lane == 0) {
            out_idx[(size_t)token * 2 + 0] = (float)besti;
            out_idx[(size_t)token * 2 + 1] = (float)best2i;
        }
    }
}

extern "C" void kernel_launch(void* const* d_in, const int* in_sizes, int n_in,
                              void* d_out, int out_size, void* d_ws, size_t ws_size,
                              hipStream_t stream) {
    const float* x = (const float*)d_in[0];
    const float* W = (const float*)d_in[1];
    const float* b = (const float*)d_in[2];

    const int E = in_sizes[2];                 // 64
    const int D = in_sizes[1] / E;             // 2048
    const int T = in_sizes[0] / D;             // 16384
    (void)E; (void)D;

    float* out_router = (float*)d_out;
    float* out_idx = out_router + (size_t)T * ROUTER_E;

    const int grid = (T + TPB - 1) / TPB;      // 1024

    topk_router_kernel<<<grid, 256, 0, stream>>>(x, W, b, out_router, out_idx, T);
}